// Round 5
// baseline (399.430 us; speedup 1.0000x reference)
//
#include <hip/hip_runtime.h>
#include <math.h>

#define NND 50000
#define DEG 16

typedef __attribute__((ext_vector_type(8))) short short8v;
typedef __attribute__((ext_vector_type(4))) float float4v;

// ---- workspace layout (bytes) ----
#define OFF_HPRE 0ULL            // N x 64 f32
#define OFF_PROJ 12800000ULL     // 4 x N x 64 f32
#define OFF_XB   64000000ULL     // N x 128 bf16
#define OFF_IDX  102400000ULL    // 5*N int
#define OFF_BQF  103600384ULL    // 4y x 8c x 8ct x 64 x 8 bf16 = 256 KB
#define OFF_WOF  103862528ULL    // 4c x 8ct x 64 x 8 bf16 = 32 KB
#define WS_NEED  103895296ULL

#define LOG2E 1.44269504088896f

__device__ __forceinline__ float fast_sig(float x){
    return __builtin_amdgcn_rcpf(1.f + __builtin_amdgcn_exp2f(-LOG2E*x));
}
__device__ __forceinline__ float fast_tanh(float x){
    return fmaf(-2.f, __builtin_amdgcn_rcpf(1.f + __builtin_amdgcn_exp2f((2.f*LOG2E)*x)), 1.f);
}
__device__ __forceinline__ unsigned short f2bf(float f){
    unsigned int u = __float_as_uint(f);
    u += 0x7FFFu + ((u >> 16) & 1u);
    return (unsigned short)(u >> 16);
}
__device__ __forceinline__ float bf2f(unsigned short h){
    return __uint_as_float(((unsigned int)h) << 16);
}

// ---------------- fused setup: iota + pack_x + pack_bqf + pack_wof ----------------
// one launch instead of four (removes 3 launch gaps). Blocks 0..6249 pack X;
// low blocks additionally handle BqF / WoF / iota.
__global__ __launch_bounds__(256) void k_setup(const float* __restrict__ na,
    const float* __restrict__ Wx, const float* __restrict__ Wh,
    const float* __restrict__ Wo, unsigned short* __restrict__ Xb,
    unsigned short* __restrict__ BqF, unsigned short* __restrict__ WoF,
    int* __restrict__ idx0)
{
    const int b = blockIdx.x, tid = threadIdx.x;
    // pack_x: i in [0, NND*32)
    {
        int i = b*256 + tid;
        if (i < NND*32){
            float4 v = *(const float4*)(na + (size_t)i*4);
            unsigned long long pk = (unsigned long long)f2bf(v.x)
                | ((unsigned long long)f2bf(v.y) << 16)
                | ((unsigned long long)f2bf(v.z) << 32)
                | ((unsigned long long)f2bf(v.w) << 48);
            *(unsigned long long*)(Xb + (size_t)i*4) = pk;
        }
    }
    if (b < 512){
        int i = b*256 + tid;  // 131072
        int jj = i & 7, lane = (i>>3)&63, ct = (i>>9)&7, c = (i>>12)&7, y = i>>15;
        int g = ct>>1, jh = ct&1, mm = lane&15, quad = lane>>4;
        int jg = (y<<5) + (jh<<4) + mm;
        int k = (c<<5) + (quad<<3) + jj;
        float v = 0.f;
        if (k < 128){
            if (g < 3) v = Wh[k*384 + g*128 + jg];
        } else {
            int kk = k - 128;
            if (g == 0)      v = Wx[kk*384 + jg];
            else if (g == 1) v = Wx[kk*384 + 128 + jg];
            else if (g == 3) v = Wx[kk*384 + 256 + jg];
        }
        BqF[i] = f2bf(v);
    } else if (b < 576){
        int i = (b-512)*256 + tid;  // 16384
        int jj = i & 7, lane = (i>>3)&63, ct = (i>>9)&7, c = i>>12;
        int n = (ct<<4) + (lane&15);
        int k = (c<<5) + ((lane>>4)<<3) + jj;
        WoF[i] = f2bf(Wo[k*128 + n]);
    } else if (b < 772){
        int i = (b-576)*256 + tid;
        if (i < NND) idx0[i] = i;
    }
}

// ---------------- walk phase (fp32, argmax determinism) ----------------
// v7: v6 tiles (256 rows, transposed-A LDS, 16x4 thread tiles) + register
// double-buffering: next chunk's A/B global loads are issued right after the
// barrier, BEFORE the compute phase; LDS store deferred past the next
// barrier. Global latency hides under the 4096-cyc compute phase.
// Load/store addresses and fmaf order identical to v6 -> bit-exact.
__global__ __launch_bounds__(256) void k_projall(const float* __restrict__ A,
    const float* __restrict__ W1, const float* __restrict__ b1,
    float* __restrict__ hpre, float* __restrict__ proj)
{
    __shared__ float Alt[32][320];     // [k][row + (row>>4)*4]  (swizzled rows, 40KB)
    __shared__ float Bl[32][68];       // [k][col] (8.7KB)
    const int tid = threadIdx.x;
    const int row0 = blockIdx.x << 8;  // 256 rows/block
    const int y = blockIdx.y;
    const float* B = W1 + (size_t)y*128*64;
    const int row_t = tid >> 4, col_t = tid & 15;   // 16 rows x 4 cols each
    float4 acc[16];
#pragma unroll
    for (int i=0;i<16;i++) acc[i] = make_float4(0.f,0.f,0.f,0.f);

    int gr = row0 + tid; if (gr >= NND) gr = NND-1;
    const float* ap = A + (size_t)gr*128;
    const int sr = tid + ((tid>>4)<<2);   // swizzled row index
    const int bk = tid >> 4, bc = (tid & 15) << 2;       // B stage r=0
    const int bk1 = (256+tid) >> 4, bc1 = (tid & 15) << 2; // r=1

    float4 pa[8];
    float4 pb0, pb1;
    // load chunk 0 into regs
#pragma unroll
    for (int u=0;u<8;u++) pa[u] = *(const float4*)(ap + (u<<2));
    pb0 = *(const float4*)(B + (size_t)bk*64 + bc);
    pb1 = *(const float4*)(B + (size_t)bk1*64 + bc1);

#pragma unroll 1
    for (int c=0;c<4;c++){
        // store staged regs to LDS
#pragma unroll
        for (int u=0;u<8;u++){
            Alt[(u<<2)+0][sr] = pa[u].x; Alt[(u<<2)+1][sr] = pa[u].y;
            Alt[(u<<2)+2][sr] = pa[u].z; Alt[(u<<2)+3][sr] = pa[u].w;
        }
        *(float4*)(&Bl[bk][bc])   = pb0;
        *(float4*)(&Bl[bk1][bc1]) = pb1;
        __syncthreads();
        // prefetch next chunk into regs (latency overlaps compute below)
        if (c < 3){
            const float* apn = ap + ((c+1)<<5);
#pragma unroll
            for (int u=0;u<8;u++) pa[u] = *(const float4*)(apn + (u<<2));
            pb0 = *(const float4*)(B + (size_t)(((c+1)<<5)+bk)*64 + bc);
            pb1 = *(const float4*)(B + (size_t)(((c+1)<<5)+bk1)*64 + bc1);
        }
        // compute on current LDS contents
#pragma unroll 2
        for (int k=0;k<32;k++){
            const float* ar = &Alt[k][row_t*20];  // row_t*16 + row_t*4 (swizzle)
            float4 a0 = *(const float4*)(ar);
            float4 a1 = *(const float4*)(ar+4);
            float4 a2 = *(const float4*)(ar+8);
            float4 a3 = *(const float4*)(ar+12);
            float4 b  = *(const float4*)(&Bl[k][col_t<<2]);
            float aa[16] = {a0.x,a0.y,a0.z,a0.w, a1.x,a1.y,a1.z,a1.w,
                            a2.x,a2.y,a2.z,a2.w, a3.x,a3.y,a3.z,a3.w};
#pragma unroll
            for (int j=0;j<16;j++){
                acc[j].x = fmaf(aa[j], b.x, acc[j].x);
                acc[j].y = fmaf(aa[j], b.y, acc[j].y);
                acc[j].z = fmaf(aa[j], b.z, acc[j].z);
                acc[j].w = fmaf(aa[j], b.w, acc[j].w);
            }
        }
        __syncthreads();
    }
    float4 bb = make_float4(0.f,0.f,0.f,0.f);
    if (y == 0) bb = *(const float4*)(b1 + (col_t<<2));
    float* dstp = (y == 0) ? hpre : (proj + (size_t)(y-1)*NND*64);
#pragma unroll
    for (int j=0;j<16;j++){
        int grr = row0 + (row_t<<4) + j;
        if (grr < NND){
            float4 o = make_float4(acc[j].x+bb.x, acc[j].y+bb.y, acc[j].z+bb.z, acc[j].w+bb.w);
            *(float4*)(dstp + ((size_t)grr<<6) + (col_t<<2)) = o;
        }
    }
}

// All 4 walk steps fused; 16 lanes per node; coalesced 256B proj-row gathers.
// v2: the post-argmax proj[sel] re-load == val[bi] (bi uniform in the
// 16-lane group; proj read-only here) -> select in-register via cndmask
// chain instead of a dependent ~600cyc L2/L3 load on the t-loop critical
// path. Bit-exact.
__global__ __launch_bounds__(256) void k_walk4(
    const float* __restrict__ hpre0, const float* __restrict__ proj,
    const int* __restrict__ dst, const float* __restrict__ W2,
    const float* __restrict__ b2, const float* __restrict__ noise,
    int* __restrict__ idxb)
{
    const int tid = threadIdx.x;
    const int sg = tid >> 4, l = tid & 15;
    const int gi = (blockIdx.x << 4) + sg;
    float4 hp = *(const float4*)(hpre0 + ((size_t)gi<<6) + (l<<2));
    float4 w2 = *(const float4*)(W2 + (l<<2));
    const float b2s = b2[0];
    int curv = gi;
#pragma unroll 1
    for (int t=0; t<4; t++){
        const float* pj = proj + (size_t)t*NND*64;
        const int nbr = dst[curv*DEG + l];
        float4 val[16];
#pragma unroll
        for (int d=0; d<16; d++){
            int nd = __shfl(nbr, d, 16);
            val[d] = *(const float4*)(pj + ((size_t)nd<<6) + (l<<2));
        }
        float lp = 0.f;
#pragma unroll
        for (int d=0; d<16; d++){
            float4 v = val[d];
            float q =  fmaxf(hp.x+v.x,0.f)*w2.x;
            q = fmaf(fmaxf(hp.y+v.y,0.f), w2.y, q);
            q = fmaf(fmaxf(hp.z+v.z,0.f), w2.z, q);
            q = fmaf(fmaxf(hp.w+v.w,0.f), w2.w, q);
            q += __shfl_xor(q, 1, 16);
            q += __shfl_xor(q, 2, 16);
            q += __shfl_xor(q, 4, 16);
            q += __shfl_xor(q, 8, 16);
            if (l == d) lp = q + b2s;
        }
        float mx = lp;
#pragma unroll
        for (int off=8; off; off>>=1) mx = fmaxf(mx, __shfl_xor(mx, off, 16));
        float s = expf(lp - mx);
#pragma unroll
        for (int off=8; off; off>>=1) s += __shfl_xor(s, off, 16);
        float p = expf(lp - mx - logf(s)) + noise[(size_t)t*NND*DEG + ((size_t)gi<<4) + l];
        float bv = p; int bi = l;
#pragma unroll
        for (int off=8; off; off>>=1){
            float ov = __shfl_xor(bv, off, 16);
            int   oi = __shfl_xor(bi, off, 16);
            if (ov > bv || (ov == bv && oi < bi)){ bv = ov; bi = oi; }
        }
        int sel = __shfl(nbr, bi, 16);
        if (l == 0) idxb[(size_t)(t+1)*NND + gi] = sel;
        // u = proj[sel] chunk l = val[bi]; bi is uniform -> register select
        float4 u = val[0];
#pragma unroll
        for (int d=1; d<16; d++){
            if (bi == d) u = val[d];
        }
        hp.x += u.x; hp.y += u.y; hp.z += u.z; hp.w += u.w;
        curv = sel;
    }
}

// ---------------- fully fused GRU (5 steps) + output GEMM ----------------
// 64 rows/block; h frags in A_l; x double-buffered; h_old in registers.
// launch_bounds(256,2): acc (128 regs) + ~116 VGPR needs the 2-wave/SIMD
// budget; (256,3) spills acc to scratch (measured r1: 239us, 300MB HBM).
// v5: skip structurally-zero B frags (c<4:ct6,7 zero; c>=4:ct4,5 zero)
// -> 25% fewer MFMA + BqF reads, bit-exact. c loops FORCED ROLLED
// (#pragma unroll 1): full unroll spilled (measured r2: VGPR 128 cap,
// 287MB FETCH scratch traffic, 219us).
__global__ __launch_bounds__(256,2) void k_gru5(
    const unsigned short* __restrict__ Xb,
    const unsigned short* __restrict__ BqF,
    const unsigned short* __restrict__ WoF,
    const float* __restrict__ bx, const float* __restrict__ bh,
    const float* __restrict__ bo, const int* __restrict__ idxb,
    float* __restrict__ out)
{
    __shared__ unsigned short A_l[8192];    // h frags [rt4][c4][64][8]
    __shared__ unsigned short X_l[16384];   // x frags, 2 buffers of 8192
    const int tid = threadIdx.x;
    const int w = tid >> 6, lane = tid & 63;
    const int m = lane & 15, quad = lane >> 4;
    const int row0 = blockIdx.x << 6;
    const int r = tid & 63, q = tid >> 6;
    int gr = row0 + r; if (gr >= NND) gr = NND-1;
    const int rt_s = r >> 4, m_s = r & 15;
    // per-thread gate biases (cols j = (w<<5)+(jh<<4)+m)
    float brr[2], bzz[2], bxn[2], bhn[2];
#pragma unroll
    for (int jh=0; jh<2; jh++){
        int j = (w<<5) + (jh<<4) + m;
        brr[jh] = bx[j] + bh[j];
        bzz[jh] = bx[128+j] + bh[128+j];
        bxn[jh] = bx[256+j];
        bhn[jh] = bh[256+j];
    }
    // h_old carried in regs as packed bf16 [jh][rt][r4]
    unsigned short holdv[2][4][4];
    // prefetch x_0, stage, prefetch x_1
    short8v xv[4];
    {
        const int xr = idxb[gr];
        const unsigned short* xrow = Xb + (size_t)xr*128 + (q<<5);
#pragma unroll
        for (int u=0;u<4;u++) xv[u] = *(const short8v*)(xrow + (u<<3));
#pragma unroll
        for (int u=0;u<4;u++)
            *(short8v*)(X_l + (((rt_s<<2)+q)*64 + (u<<4) + m_s)*8) = xv[u];
        const int xr1 = idxb[NND + gr];
        const unsigned short* xrow1 = Xb + (size_t)xr1*128 + (q<<5);
#pragma unroll
        for (int u=0;u<4;u++) xv[u] = *(const short8v*)(xrow1 + (u<<3));
    }
    __syncthreads();

#pragma unroll 1
    for (int s=0; s<5; s++){
        const unsigned short* Xcur = X_l + ((s&1)<<13);
        float4v zero = {0.f,0.f,0.f,0.f};
        float4v acc[32];   // [ct8][rt4]
#pragma unroll
        for (int i=0;i<32;i++) acc[i] = zero;
        // h-part: c=0..3 from A_l; ct=6,7 (xn gate) are zero over h rows -> skip
        if (s > 0){
#pragma unroll 1
            for (int c=0;c<4;c++){
                short8v afr[4];
#pragma unroll
                for (int rt=0;rt<4;rt++)
                    afr[rt] = *(const short8v*)(A_l + (((rt<<2) + c)*64 + lane)*8);
                const unsigned short* bp = BqF + ((((size_t)w*8 + c)*8)*64 + lane)*8;
#pragma unroll
                for (int ct=0;ct<6;ct++){
                    short8v bf = *(const short8v*)(bp + (ct<<9));
#pragma unroll
                    for (int rt=0;rt<4;rt++)
                        acc[(ct<<2)+rt] = __builtin_amdgcn_mfma_f32_16x16x32_bf16(afr[rt], bf, acc[(ct<<2)+rt], 0,0,0);
                }
            }
        }
        // x-part: c=4..7 from Xcur; ct=4,5 (hn gate) are zero over x rows -> skip
#pragma unroll 1
        for (int c=4;c<8;c++){
            short8v afr[4];
#pragma unroll
            for (int rt=0;rt<4;rt++)
                afr[rt] = *(const short8v*)(Xcur + (((rt<<2) + (c&3))*64 + lane)*8);
            const unsigned short* bp = BqF + ((((size_t)w*8 + c)*8)*64 + lane)*8;
#pragma unroll
            for (int cti=0;cti<6;cti++){
                const int ct = (cti < 4) ? cti : (cti + 2);
                short8v bf = *(const short8v*)(bp + (ct<<9));
#pragma unroll
                for (int rt=0;rt<4;rt++)
                    acc[(ct<<2)+rt] = __builtin_amdgcn_mfma_f32_16x16x32_bf16(afr[rt], bf, acc[(ct<<2)+rt], 0,0,0);
            }
        }
        // stage x_{s+1} into the other buffer; prefetch x_{s+2}
        if (s < 4){
            unsigned short* Xnxt = X_l + (((s+1)&1)<<13);
#pragma unroll
            for (int u=0;u<4;u++)
                *(short8v*)(Xnxt + (((rt_s<<2)+q)*64 + (u<<4) + m_s)*8) = xv[u];
            if (s < 3){
                const int xr = idxb[(size_t)(s+2)*NND + gr];
                const unsigned short* xrow = Xb + (size_t)xr*128 + (q<<5);
#pragma unroll
                for (int u=0;u<4;u++) xv[u] = *(const short8v*)(xrow + (u<<3));
            }
        }
        // epilogue: fast gates, h_old from regs
#pragma unroll
        for (int jh=0; jh<2; jh++){
#pragma unroll
            for (int rt=0; rt<4; rt++){
#pragma unroll
                for (int r4=0; r4<4; r4++){
                    float rg = fast_sig(acc[(jh<<2)+rt][r4] + brr[jh]);
                    float zg = fast_sig(acc[((2+jh)<<2)+rt][r4] + bzz[jh]);
                    float ng = fast_tanh(acc[((6+jh)<<2)+rt][r4] + bxn[jh] + rg*(acc[((4+jh)<<2)+rt][r4] + bhn[jh]));
                    float hold = (s == 0) ? 0.f : bf2f(holdv[jh][rt][r4]);
                    holdv[jh][rt][r4] = f2bf((1.f - zg)*ng + zg*hold);
                }
            }
        }
        __syncthreads();   // all A_l/X_l reads of this step done
#pragma unroll
        for (int jh=0; jh<2; jh++)
#pragma unroll
            for (int rt=0; rt<4; rt++)
#pragma unroll
                for (int r4=0; r4<4; r4++){
                    int ha = ((((rt<<2)+w)*64 + (((jh<<1)+(m>>3))<<4) + (quad<<2)+r4)<<3) + (m&7);
                    A_l[ha] = holdv[jh][rt][r4];
                }
        __syncthreads();   // A_l ready for next step / out-GEMM
    }
    // output GEMM: wave w -> cols (w<<5)..(w<<5)+31, K=128
    float4v zero = {0.f,0.f,0.f,0.f};
    float4v acco[8];   // [cto2][rt4]
#pragma unroll
    for (int i=0;i<8;i++) acco[i] = zero;
    for (int c=0;c<4;c++){
        short8v afr[4];
#pragma unroll
        for (int rt=0;rt<4;rt++)
            afr[rt] = *(const short8v*)(A_l + (((rt<<2) + c)*64 + lane)*8);
#pragma unroll
        for (int cto=0;cto<2;cto++){
            short8v bf = *(const short8v*)(WoF + (((size_t)(c*8 + (w<<1)+cto))*64 + lane)*8);
#pragma unroll
            for (int rt=0;rt<4;rt++)
                acco[(cto<<2)+rt] = __builtin_amdgcn_mfma_f32_16x16x32_bf16(afr[rt], bf, acco[(cto<<2)+rt], 0,0,0);
        }
    }
#pragma unroll
    for (int cto=0; cto<2; cto++){
        int col = (w<<5) + (cto<<4) + m;
        float bb = bo[col];
#pragma unroll
        for (int rt=0; rt<4; rt++){
#pragma unroll
            for (int r4=0; r4<4; r4++){
                int row = row0 + (rt<<4) + (quad<<2) + r4;
                if (row < NND) out[(size_t)row*128 + col] = acco[(cto<<2)+rt][r4] + bb;
            }
        }
    }
}

extern "C" void kernel_launch(void* const* d_in, const int* in_sizes, int n_in,
                              void* d_out, int out_size, void* d_ws, size_t ws_size,
                              hipStream_t stream)
{
    const float* node_attr = (const float*)d_in[0];
    const int*   edge_index= (const int*)  d_in[1];
    const float* noise = (const float*)d_in[3];
    const float* W1 = (const float*)d_in[4];
    const float* b1 = (const float*)d_in[5];
    const float* W2 = (const float*)d_in[6];
    const float* b2 = (const float*)d_in[7];
    const float* Wx = (const float*)d_in[8];
    const float* Wh = (const float*)d_in[9];
    const float* bx = (const float*)d_in[10];
    const float* bh = (const float*)d_in[11];
    const float* Wo = (const float*)d_in[12];
    const float* bo = (const float*)d_in[13];
    const int* dst = edge_index + (size_t)NND*DEG;
    float* out = (float*)d_out;
    if (ws_size < WS_NEED) return;

    char* ws = (char*)d_ws;
    float* hpre = (float*)(ws + OFF_HPRE);
    float* proj = (float*)(ws + OFF_PROJ);
    unsigned short* Xb  = (unsigned short*)(ws + OFF_XB);
    int* idxb = (int*)(ws + OFF_IDX);
    unsigned short* BqF = (unsigned short*)(ws + OFF_BQF);
    unsigned short* WoF = (unsigned short*)(ws + OFF_WOF);

    // fused setup: pack X/BqF/WoF + iota, one launch
    k_setup<<<dim3(6250), dim3(256), 0, stream>>>(node_attr, Wx, Wh, Wo, Xb, BqF, WoF, idxb);

    // walk phase (fp32): 256-row tiles, transposed-A LDS, reg double-buffer
    k_projall<<<dim3(196, 5), dim3(256), 0, stream>>>(node_attr, W1, b1, hpre, proj);
    k_walk4<<<dim3(3125), dim3(256), 0, stream>>>(hpre, proj, dst, W2, b2, noise, idxb);

    // GRU (all 5 steps) + output GEMM, one kernel
    k_gru5<<<dim3(782), dim3(256), 0, stream>>>(Xb, BqF, WoF, bx, bh, bo, idxb, out);
}

// Round 6
// 358.123 us; speedup vs baseline: 1.1153x; 1.1153x over previous
//
#include <hip/hip_runtime.h>
#include <math.h>

#define NND 50000
#define DEG 16

typedef __attribute__((ext_vector_type(8))) short short8v;
typedef __attribute__((ext_vector_type(4))) float float4v;

// ---- workspace layout (bytes) ----
#define OFF_HPRE 0ULL            // N x 64 f32
#define OFF_PROJ 12800000ULL     // 4 x N x 64 f32
#define OFF_XB   64000000ULL     // N x 128 bf16
#define OFF_IDX  102400000ULL    // 5*N int
#define OFF_BQF  103600384ULL    // 4y x 8c x 8ct x 64 x 8 bf16 = 256 KB
#define OFF_WOF  103862528ULL    // 4c x 8ct x 64 x 8 bf16 = 32 KB
#define WS_NEED  103895296ULL

#define LOG2E 1.44269504088896f

__device__ __forceinline__ float fast_sig(float x){
    return __builtin_amdgcn_rcpf(1.f + __builtin_amdgcn_exp2f(-LOG2E*x));
}
__device__ __forceinline__ float fast_tanh(float x){
    return fmaf(-2.f, __builtin_amdgcn_rcpf(1.f + __builtin_amdgcn_exp2f((2.f*LOG2E)*x)), 1.f);
}
__device__ __forceinline__ unsigned short f2bf(float f){
    unsigned int u = __float_as_uint(f);
    u += 0x7FFFu + ((u >> 16) & 1u);
    return (unsigned short)(u >> 16);
}
__device__ __forceinline__ float bf2f(unsigned short h){
    return __uint_as_float(((unsigned int)h) << 16);
}

// ---------------- fused setup: iota + pack_x + pack_bqf + pack_wof ----------------
__global__ __launch_bounds__(256) void k_setup(const float* __restrict__ na,
    const float* __restrict__ Wx, const float* __restrict__ Wh,
    const float* __restrict__ Wo, unsigned short* __restrict__ Xb,
    unsigned short* __restrict__ BqF, unsigned short* __restrict__ WoF,
    int* __restrict__ idx0)
{
    const int b = blockIdx.x, tid = threadIdx.x;
    {
        int i = b*256 + tid;
        if (i < NND*32){
            float4 v = *(const float4*)(na + (size_t)i*4);
            unsigned long long pk = (unsigned long long)f2bf(v.x)
                | ((unsigned long long)f2bf(v.y) << 16)
                | ((unsigned long long)f2bf(v.z) << 32)
                | ((unsigned long long)f2bf(v.w) << 48);
            *(unsigned long long*)(Xb + (size_t)i*4) = pk;
        }
    }
    if (b < 512){
        int i = b*256 + tid;  // 131072
        int jj = i & 7, lane = (i>>3)&63, ct = (i>>9)&7, c = (i>>12)&7, y = i>>15;
        int g = ct>>1, jh = ct&1, mm = lane&15, quad = lane>>4;
        int jg = (y<<5) + (jh<<4) + mm;
        int k = (c<<5) + (quad<<3) + jj;
        float v = 0.f;
        if (k < 128){
            if (g < 3) v = Wh[k*384 + g*128 + jg];
        } else {
            int kk = k - 128;
            if (g == 0)      v = Wx[kk*384 + jg];
            else if (g == 1) v = Wx[kk*384 + 128 + jg];
            else if (g == 3) v = Wx[kk*384 + 256 + jg];
        }
        BqF[i] = f2bf(v);
    } else if (b < 576){
        int i = (b-512)*256 + tid;  // 16384
        int jj = i & 7, lane = (i>>3)&63, ct = (i>>9)&7, c = i>>12;
        int n = (ct<<4) + (lane&15);
        int k = (c<<5) + ((lane>>4)<<3) + jj;
        WoF[i] = f2bf(Wo[k*128 + n]);
    } else if (b < 772){
        int i = (b-576)*256 + tid;
        if (i < NND) idx0[i] = i;
    }
}

// ---------------- walk phase (fp32, argmax determinism) ----------------
// v6 (round-4 known-good): 256-row x 64-col tile, thread = 16 rows x 4 cols,
// A transposed in LDS with +4-per-16-rows swizzle. v7's reg double-buffer
// reverted (measured r5: ~neutral; +36 VGPR risk, no gain).
__global__ __launch_bounds__(256) void k_projall(const float* __restrict__ A,
    const float* __restrict__ W1, const float* __restrict__ b1,
    float* __restrict__ hpre, float* __restrict__ proj)
{
    __shared__ float Alt[32][320];     // [k][row + (row>>4)*4]  (swizzled rows, 40KB)
    __shared__ float Bl[32][68];       // [k][col] (8.7KB)
    const int tid = threadIdx.x;
    const int row0 = blockIdx.x << 8;  // 256 rows/block
    const int y = blockIdx.y;
    const float* B = W1 + (size_t)y*128*64;
    const int row_t = tid >> 4, col_t = tid & 15;   // 16 rows x 4 cols each
    float4 acc[16];
#pragma unroll
    for (int i=0;i<16;i++) acc[i] = make_float4(0.f,0.f,0.f,0.f);

    for (int k0 = 0; k0 < 128; k0 += 32){
        {
            int gr = row0 + tid; if (gr >= NND) gr = NND-1;
            const float* ap = A + (size_t)gr*128 + k0;
            const int sr = tid + ((tid>>4)<<2);   // swizzled row index
#pragma unroll
            for (int u=0;u<8;u++){
                float4 v = *(const float4*)(ap + (u<<2));
                Alt[(u<<2)+0][sr] = v.x; Alt[(u<<2)+1][sr] = v.y;
                Alt[(u<<2)+2][sr] = v.z; Alt[(u<<2)+3][sr] = v.w;
            }
        }
#pragma unroll
        for (int r=0;r<2;r++){
            int p = (r<<8) + tid;
            int bk = p >> 4, bc = (p & 15) << 2;
            *(float4*)(&Bl[bk][bc]) = *(const float4*)(B + (size_t)(k0+bk)*64 + bc);
        }
        __syncthreads();
#pragma unroll 2
        for (int k=0;k<32;k++){
            const float* ar = &Alt[k][row_t*20];  // row_t*16 + row_t*4 (swizzle)
            float4 a0 = *(const float4*)(ar);
            float4 a1 = *(const float4*)(ar+4);
            float4 a2 = *(const float4*)(ar+8);
            float4 a3 = *(const float4*)(ar+12);
            float4 b  = *(const float4*)(&Bl[k][col_t<<2]);
            float aa[16] = {a0.x,a0.y,a0.z,a0.w, a1.x,a1.y,a1.z,a1.w,
                            a2.x,a2.y,a2.z,a2.w, a3.x,a3.y,a3.z,a3.w};
#pragma unroll
            for (int j=0;j<16;j++){
                acc[j].x = fmaf(aa[j], b.x, acc[j].x);
                acc[j].y = fmaf(aa[j], b.y, acc[j].y);
                acc[j].z = fmaf(aa[j], b.z, acc[j].z);
                acc[j].w = fmaf(aa[j], b.w, acc[j].w);
            }
        }
        __syncthreads();
    }
    float4 bb = make_float4(0.f,0.f,0.f,0.f);
    if (y == 0) bb = *(const float4*)(b1 + (col_t<<2));
    float* dstp = (y == 0) ? hpre : (proj + (size_t)(y-1)*NND*64);
#pragma unroll
    for (int j=0;j<16;j++){
        int gr = row0 + (row_t<<4) + j;
        if (gr < NND){
            float4 o = make_float4(acc[j].x+bb.x, acc[j].y+bb.y, acc[j].z+bb.z, acc[j].w+bb.w);
            *(float4*)(dstp + ((size_t)gr<<6) + (col_t<<2)) = o;
        }
    }
}

// All 4 walk steps fused; 16 lanes per node; coalesced 256B proj-row gathers.
// round-3 version (known-good, 44 VGPR). The r5 register-select variant
// regressed: keeping val[16] live across the argmax raised VGPR 44->60,
// collapsed load batching/MLP (HBM 3.5->2.1 TB/s, 107->151us). The
// dependent re-load of proj[sel] stays.
__global__ __launch_bounds__(256) void k_walk4(
    const float* __restrict__ hpre0, const float* __restrict__ proj,
    const int* __restrict__ dst, const float* __restrict__ W2,
    const float* __restrict__ b2, const float* __restrict__ noise,
    int* __restrict__ idxb)
{
    const int tid = threadIdx.x;
    const int sg = tid >> 4, l = tid & 15;
    const int gi = (blockIdx.x << 4) + sg;
    float4 hp = *(const float4*)(hpre0 + ((size_t)gi<<6) + (l<<2));
    float4 w2 = *(const float4*)(W2 + (l<<2));
    const float b2s = b2[0];
    int curv = gi;
#pragma unroll 1
    for (int t=0; t<4; t++){
        const float* pj = proj + (size_t)t*NND*64;
        const int nbr = dst[curv*DEG + l];
        float4 val[16];
#pragma unroll
        for (int d=0; d<16; d++){
            int nd = __shfl(nbr, d, 16);
            val[d] = *(const float4*)(pj + ((size_t)nd<<6) + (l<<2));
        }
        float lp = 0.f;
#pragma unroll
        for (int d=0; d<16; d++){
            float4 v = val[d];
            float q =  fmaxf(hp.x+v.x,0.f)*w2.x;
            q = fmaf(fmaxf(hp.y+v.y,0.f), w2.y, q);
            q = fmaf(fmaxf(hp.z+v.z,0.f), w2.z, q);
            q = fmaf(fmaxf(hp.w+v.w,0.f), w2.w, q);
            q += __shfl_xor(q, 1, 16);
            q += __shfl_xor(q, 2, 16);
            q += __shfl_xor(q, 4, 16);
            q += __shfl_xor(q, 8, 16);
            if (l == d) lp = q + b2s;
        }
        float mx = lp;
#pragma unroll
        for (int off=8; off; off>>=1) mx = fmaxf(mx, __shfl_xor(mx, off, 16));
        float s = expf(lp - mx);
#pragma unroll
        for (int off=8; off; off>>=1) s += __shfl_xor(s, off, 16);
        float p = expf(lp - mx - logf(s)) + noise[(size_t)t*NND*DEG + ((size_t)gi<<4) + l];
        float bv = p; int bi = l;
#pragma unroll
        for (int off=8; off; off>>=1){
            float ov = __shfl_xor(bv, off, 16);
            int   oi = __shfl_xor(bi, off, 16);
            if (ov > bv || (ov == bv && oi < bi)){ bv = ov; bi = oi; }
        }
        int sel = __shfl(nbr, bi, 16);
        if (l == 0) idxb[(size_t)(t+1)*NND + gi] = sel;
        float4 u = *(const float4*)(pj + ((size_t)sel<<6) + (l<<2));
        hp.x += u.x; hp.y += u.y; hp.z += u.z; hp.w += u.w;
        curv = sel;
    }
}

// ---------------- fully fused GRU (5 steps) + output GEMM ----------------
// v6: A_l double-buffered (step s reads A_l[s&1], writes A_l[(s+1)&1]) ->
// ONE barrier per step (was 2; writes never alias concurrent reads).
// 512-block grid-stride over 782 tiles (resident blocks chain into tile 2,
// no re-dispatch). LDS 64KB/block -> still 2 blocks/CU.
// launch_bounds(256,2): acc(128)+VGPR(~116) needs the 2-wave/SIMD budget;
// (256,3) spills (r1: 239us). c loops FORCED ROLLED (r2: unroll spills).
// Zero-frag skip (c<4:ct6,7; c>=4:ct4,5) is bit-exact.
__global__ __launch_bounds__(256,2) void k_gru5(
    const unsigned short* __restrict__ Xb,
    const unsigned short* __restrict__ BqF,
    const unsigned short* __restrict__ WoF,
    const float* __restrict__ bx, const float* __restrict__ bh,
    const float* __restrict__ bo, const int* __restrict__ idxb,
    float* __restrict__ out)
{
    __shared__ unsigned short A_l[2][8192];  // h frags, double-buffered (32KB)
    __shared__ unsigned short X_l[16384];    // x frags, 2 buffers of 8192 (32KB)
    const int tid = threadIdx.x;
    const int w = tid >> 6, lane = tid & 63;
    const int m = lane & 15, quad = lane >> 4;
    const int r = tid & 63, q = tid >> 6;
    const int rt_s = r >> 4, m_s = r & 15;
    // per-thread gate biases (cols j = (w<<5)+(jh<<4)+m) — tile-independent
    float brr[2], bzz[2], bxn[2], bhn[2];
#pragma unroll
    for (int jh=0; jh<2; jh++){
        int j = (w<<5) + (jh<<4) + m;
        brr[jh] = bx[j] + bh[j];
        bzz[jh] = bx[128+j] + bh[128+j];
        bxn[jh] = bx[256+j];
        bhn[jh] = bh[256+j];
    }

#pragma unroll 1
    for (int tb = blockIdx.x; tb < 782; tb += 512){
        const int row0 = tb << 6;
        int gr = row0 + r; if (gr >= NND) gr = NND-1;
        // h_old carried in regs as packed bf16 [jh][rt][r4]
        unsigned short holdv[2][4][4];
        // prefetch x_0, stage into X buffer 0, prefetch x_1
        short8v xv[4];
        {
            const int xr = idxb[gr];
            const unsigned short* xrow = Xb + (size_t)xr*128 + (q<<5);
#pragma unroll
            for (int u=0;u<4;u++) xv[u] = *(const short8v*)(xrow + (u<<3));
#pragma unroll
            for (int u=0;u<4;u++)
                *(short8v*)(X_l + (((rt_s<<2)+q)*64 + (u<<4) + m_s)*8) = xv[u];
            const int xr1 = idxb[NND + gr];
            const unsigned short* xrow1 = Xb + (size_t)xr1*128 + (q<<5);
#pragma unroll
            for (int u=0;u<4;u++) xv[u] = *(const short8v*)(xrow1 + (u<<3));
        }
        __syncthreads();   // X_l[0] ready (also guards prev tile's A_l[1] reads)

#pragma unroll 1
        for (int s=0; s<5; s++){
            const unsigned short* Acur = A_l[s&1];
            const unsigned short* Xcur = X_l + ((s&1)<<13);
            float4v zero = {0.f,0.f,0.f,0.f};
            float4v acc[32];   // [ct8][rt4]
#pragma unroll
            for (int i=0;i<32;i++) acc[i] = zero;
            // h-part: c=0..3 from Acur; ct=6,7 (xn gate) zero over h rows -> skip
            if (s > 0){
#pragma unroll 1
                for (int c=0;c<4;c++){
                    short8v afr[4];
#pragma unroll
                    for (int rt=0;rt<4;rt++)
                        afr[rt] = *(const short8v*)(Acur + (((rt<<2) + c)*64 + lane)*8);
                    const unsigned short* bp = BqF + ((((size_t)w*8 + c)*8)*64 + lane)*8;
#pragma unroll
                    for (int ct=0;ct<6;ct++){
                        short8v bf = *(const short8v*)(bp + (ct<<9));
#pragma unroll
                        for (int rt=0;rt<4;rt++)
                            acc[(ct<<2)+rt] = __builtin_amdgcn_mfma_f32_16x16x32_bf16(afr[rt], bf, acc[(ct<<2)+rt], 0,0,0);
                    }
                }
            }
            // x-part: c=4..7 from Xcur; ct=4,5 (hn gate) zero over x rows -> skip
#pragma unroll 1
            for (int c=4;c<8;c++){
                short8v afr[4];
#pragma unroll
                for (int rt=0;rt<4;rt++)
                    afr[rt] = *(const short8v*)(Xcur + (((rt<<2) + (c&3))*64 + lane)*8);
                const unsigned short* bp = BqF + ((((size_t)w*8 + c)*8)*64 + lane)*8;
#pragma unroll
                for (int cti=0;cti<6;cti++){
                    const int ct = (cti < 4) ? cti : (cti + 2);
                    short8v bf = *(const short8v*)(bp + (ct<<9));
#pragma unroll
                    for (int rt=0;rt<4;rt++)
                        acc[(ct<<2)+rt] = __builtin_amdgcn_mfma_f32_16x16x32_bf16(afr[rt], bf, acc[(ct<<2)+rt], 0,0,0);
                }
            }
            // stage x_{s+1} into the other X buffer; prefetch x_{s+2}
            if (s < 4){
                unsigned short* Xnxt = X_l + (((s+1)&1)<<13);
#pragma unroll
                for (int u=0;u<4;u++)
                    *(short8v*)(Xnxt + (((rt_s<<2)+q)*64 + (u<<4) + m_s)*8) = xv[u];
                if (s < 3){
                    const int xr = idxb[(size_t)(s+2)*NND + gr];
                    const unsigned short* xrow = Xb + (size_t)xr*128 + (q<<5);
#pragma unroll
                    for (int u=0;u<4;u++) xv[u] = *(const short8v*)(xrow + (u<<3));
                }
            }
            // epilogue: fast gates, h_old from regs
#pragma unroll
            for (int jh=0; jh<2; jh++){
#pragma unroll
                for (int rt=0; rt<4; rt++){
#pragma unroll
                    for (int r4=0; r4<4; r4++){
                        float rg = fast_sig(acc[(jh<<2)+rt][r4] + brr[jh]);
                        float zg = fast_sig(acc[((2+jh)<<2)+rt][r4] + bzz[jh]);
                        float ng = fast_tanh(acc[((6+jh)<<2)+rt][r4] + bxn[jh] + rg*(acc[((4+jh)<<2)+rt][r4] + bhn[jh]));
                        float hold = (s == 0) ? 0.f : bf2f(holdv[jh][rt][r4]);
                        holdv[jh][rt][r4] = f2bf((1.f - zg)*ng + zg*hold);
                    }
                }
            }
            // write h to the OTHER A buffer (no alias with this step's reads)
            unsigned short* Anxt = A_l[(s+1)&1];
#pragma unroll
            for (int jh=0; jh<2; jh++)
#pragma unroll
                for (int rt=0; rt<4; rt++)
#pragma unroll
                    for (int r4=0; r4<4; r4++){
                        int ha = ((((rt<<2)+w)*64 + (((jh<<1)+(m>>3))<<4) + (quad<<2)+r4)<<3) + (m&7);
                        Anxt[ha] = holdv[jh][rt][r4];
                    }
            __syncthreads();   // single barrier: A_l[(s+1)&1]/X_l[(s+1)&1] ready
        }
        // output GEMM: h final in A_l[1]; wave w -> cols (w<<5)..(w<<5)+31
        const unsigned short* Afin = A_l[1];
        float4v zero = {0.f,0.f,0.f,0.f};
        float4v acco[8];   // [cto2][rt4]
#pragma unroll
        for (int i=0;i<8;i++) acco[i] = zero;
#pragma unroll 1
        for (int c=0;c<4;c++){
            short8v afr[4];
#pragma unroll
            for (int rt=0;rt<4;rt++)
                afr[rt] = *(const short8v*)(Afin + (((rt<<2) + c)*64 + lane)*8);
#pragma unroll
            for (int cto=0;cto<2;cto++){
                short8v bf = *(const short8v*)(WoF + (((size_t)(c*8 + (w<<1)+cto))*64 + lane)*8);
#pragma unroll
                for (int rt=0;rt<4;rt++)
                    acco[(cto<<2)+rt] = __builtin_amdgcn_mfma_f32_16x16x32_bf16(afr[rt], bf, acco[(cto<<2)+rt], 0,0,0);
            }
        }
#pragma unroll
        for (int cto=0; cto<2; cto++){
            int col = (w<<5) + (cto<<4) + m;
            float bb = bo[col];
#pragma unroll
            for (int rt=0; rt<4; rt++){
#pragma unroll
                for (int r4=0; r4<4; r4++){
                    int row = row0 + (rt<<4) + (quad<<2) + r4;
                    if (row < NND) out[(size_t)row*128 + col] = acco[(cto<<2)+rt][r4] + bb;
                }
            }
        }
    }
}

extern "C" void kernel_launch(void* const* d_in, const int* in_sizes, int n_in,
                              void* d_out, int out_size, void* d_ws, size_t ws_size,
                              hipStream_t stream)
{
    const float* node_attr = (const float*)d_in[0];
    const int*   edge_index= (const int*)  d_in[1];
    const float* noise = (const float*)d_in[3];
    const float* W1 = (const float*)d_in[4];
    const float* b1 = (const float*)d_in[5];
    const float* W2 = (const float*)d_in[6];
    const float* b2 = (const float*)d_in[7];
    const float* Wx = (const float*)d_in[8];
    const float* Wh = (const float*)d_in[9];
    const float* bx = (const float*)d_in[10];
    const float* bh = (const float*)d_in[11];
    const float* Wo = (const float*)d_in[12];
    const float* bo = (const float*)d_in[13];
    const int* dst = edge_index + (size_t)NND*DEG;
    float* out = (float*)d_out;
    if (ws_size < WS_NEED) return;

    char* ws = (char*)d_ws;
    float* hpre = (float*)(ws + OFF_HPRE);
    float* proj = (float*)(ws + OFF_PROJ);
    unsigned short* Xb  = (unsigned short*)(ws + OFF_XB);
    int* idxb = (int*)(ws + OFF_IDX);
    unsigned short* BqF = (unsigned short*)(ws + OFF_BQF);
    unsigned short* WoF = (unsigned short*)(ws + OFF_WOF);

    // fused setup: pack X/BqF/WoF + iota, one launch
    k_setup<<<dim3(6250), dim3(256), 0, stream>>>(node_attr, Wx, Wh, Wo, Xb, BqF, WoF, idxb);

    // walk phase (fp32): v6 tiles (known-good)
    k_projall<<<dim3(196, 5), dim3(256), 0, stream>>>(node_attr, W1, b1, hpre, proj);
    k_walk4<<<dim3(3125), dim3(256), 0, stream>>>(hpre, proj, dst, W2, b2, noise, idxb);

    // GRU (all 5 steps) + output GEMM: 512 persistent-ish blocks, 1 barrier/step
    k_gru5<<<dim3(512), dim3(256), 0, stream>>>(Xb, BqF, WoF, bx, bh, bo, idxb, out);
}